// Round 1
// baseline (1361.204 us; speedup 1.0000x reference)
//
#include <hip/hip_runtime.h>
#include <hip/hip_bf16.h>
#include <stdint.h>

typedef __hip_bfloat16 bf16;
typedef __bf16 bf16x8 __attribute__((ext_vector_type(8)));
typedef float f32x4 __attribute__((ext_vector_type(4)));

#define NEDGE 500000
#define NUN   50000
#define NVN   50000
#define NNODE 50000   // == NUN == NVN

__device__ __forceinline__ float b2f(bf16 v) { return __bfloat162float(v); }

// ---------------------------------------------------------------------------
// Node GEMM: C[N,dout] = A[N,din] @ W[din,dout] + bias.
// A: f32 (A_BF16=false) or bf16 (A_BF16=true). W/bias: f32 (converted to bf16
// fragments on the fly). Out: f32 or bf16 per OUT_BF16.
// Block = 256 (4 waves); block tile = 64 rows; wave tile = 16 rows.
// MFMA 16x16x32 bf16. A frag: A[m=lane&15][k=quad*8+j]. C/D: col=lane&15,
// row=quad*4+reg (m89-verified).
// ---------------------------------------------------------------------------
template<bool A_BF16, bool OUT_BF16>
__global__ __launch_bounds__(256) void gemm_node(
    const void* __restrict__ A_, const float* __restrict__ W,
    const float* __restrict__ bias, int N, int din, int dout,
    void* __restrict__ out_, int ostride, int ocol)
{
    __shared__ __align__(16) bf16 wt[26112]; // max dout*(din+8) = 192*136
    const int tid = threadIdx.x;
    const int stride = din + 8; // rows stay 16B-aligned (din mult of 8)
    for (int k = 0; k < din; ++k) {
        if (tid < dout) wt[tid * stride + k] = __float2bfloat16(W[k * dout + tid]);
    }
    __syncthreads();

    const int wave = tid >> 6, lane = tid & 63;
    const int m16 = lane & 15, quad = lane >> 4;
    const int row0 = blockIdx.x * 64 + wave * 16;
    int arow = row0 + m16; if (arow >= N) arow = N - 1;

    const bf16*  aptrb = A_BF16 ? ((const bf16*)A_) + (size_t)arow * din + quad * 8 : nullptr;
    const float* aptrf = A_BF16 ? nullptr : ((const float*)A_) + (size_t)arow * din + quad * 8;

    const int nct = dout >> 4;
    for (int ct = 0; ct < nct; ++ct) {
        f32x4 acc = {0.f, 0.f, 0.f, 0.f};
        const bf16* bbase = &wt[(ct * 16 + m16) * stride + quad * 8];
        for (int k0 = 0; k0 < din; k0 += 32) {
            bf16x8 af;
            if (A_BF16) {
                af = *(const bf16x8*)(aptrb + k0);
            } else {
                float4 f0 = *(const float4*)(aptrf + k0);
                float4 f1 = *(const float4*)(aptrf + k0 + 4);
                af[0] = (__bf16)f0.x; af[1] = (__bf16)f0.y;
                af[2] = (__bf16)f0.z; af[3] = (__bf16)f0.w;
                af[4] = (__bf16)f1.x; af[5] = (__bf16)f1.y;
                af[6] = (__bf16)f1.z; af[7] = (__bf16)f1.w;
            }
            bf16x8 bfr = *(const bf16x8*)(bbase + k0);
            acc = __builtin_amdgcn_mfma_f32_16x16x32_bf16(af, bfr, acc, 0, 0, 0);
        }
        const int c = ct * 16 + m16;
        const float bv = bias[c];
        #pragma unroll
        for (int r = 0; r < 4; ++r) {
            int row = row0 + quad * 4 + r;
            if (row < N) {
                size_t idx = (size_t)row * ostride + ocol + c;
                float val = acc[r] + bv;
                if (OUT_BF16) ((bf16*)out_)[idx] = __float2bfloat16(val);
                else          ((float*)out_)[idx] = val;
            }
        }
    }
}

// ---------------------------------------------------------------------------
// Edge GEMM fused with gather-add epilogue (f32 in, f32 out):
// he[e,:] = e_feat[e,:]@e_lin_w + e_lin_b + he_u[u_idx[e],:] + he_v[v_idx[e],:]
// he_u/he_v are bf16 workspace buffers.
// ---------------------------------------------------------------------------
__global__ __launch_bounds__(256) void gemm_edge(
    const float* __restrict__ A, const float* __restrict__ W,
    const float* __restrict__ bias,
    const int* __restrict__ u_idx, const int* __restrict__ v_idx,
    const bf16* __restrict__ he_u, const bf16* __restrict__ he_v,
    float* __restrict__ out)
{
    __shared__ __align__(16) bf16 wt[128 * 72];
    const int din = 64, dout = 128, stride = 72;
    const int tid = threadIdx.x;
    for (int k = 0; k < din; ++k) {
        if (tid < dout) wt[tid * stride + k] = __float2bfloat16(W[k * dout + tid]);
    }
    __syncthreads();

    const int wave = tid >> 6, lane = tid & 63;
    const int m16 = lane & 15, quad = lane >> 4;
    const int row0 = blockIdx.x * 64 + wave * 16;
    int arow = row0 + m16; if (arow >= NEDGE) arow = NEDGE - 1;
    const float* aptr = A + (size_t)arow * din + quad * 8;

    bf16x8 af;
    {
        float4 f0 = *(const float4*)(aptr);
        float4 f1 = *(const float4*)(aptr + 4);
        af[0] = (__bf16)f0.x; af[1] = (__bf16)f0.y;
        af[2] = (__bf16)f0.z; af[3] = (__bf16)f0.w;
        af[4] = (__bf16)f1.x; af[5] = (__bf16)f1.y;
        af[6] = (__bf16)f1.z; af[7] = (__bf16)f1.w;
    }
    bf16x8 af2;
    {
        float4 f0 = *(const float4*)(aptr + 32);
        float4 f1 = *(const float4*)(aptr + 36);
        af2[0] = (__bf16)f0.x; af2[1] = (__bf16)f0.y;
        af2[2] = (__bf16)f0.z; af2[3] = (__bf16)f0.w;
        af2[4] = (__bf16)f1.x; af2[5] = (__bf16)f1.y;
        af2[6] = (__bf16)f1.z; af2[7] = (__bf16)f1.w;
    }

    int us[4], vs[4];
    #pragma unroll
    for (int r = 0; r < 4; ++r) {
        int row = row0 + quad * 4 + r;
        int rc = row < NEDGE ? row : NEDGE - 1;
        us[r] = u_idx[rc];
        vs[r] = v_idx[rc];
    }

    for (int ct = 0; ct < 8; ++ct) {
        f32x4 acc = {0.f, 0.f, 0.f, 0.f};
        const bf16* bbase = &wt[(ct * 16 + m16) * stride + quad * 8];
        bf16x8 b0 = *(const bf16x8*)(bbase);
        bf16x8 b1 = *(const bf16x8*)(bbase + 32);
        acc = __builtin_amdgcn_mfma_f32_16x16x32_bf16(af,  b0, acc, 0, 0, 0);
        acc = __builtin_amdgcn_mfma_f32_16x16x32_bf16(af2, b1, acc, 0, 0, 0);
        const int c = ct * 16 + m16;
        const float bv = bias[c];
        #pragma unroll
        for (int r = 0; r < 4; ++r) {
            int row = row0 + quad * 4 + r;
            if (row < NEDGE) {
                float val = acc[r] + bv
                          + b2f(he_u[(size_t)us[r] * 128 + c])
                          + b2f(he_v[(size_t)vs[r] * 128 + c]);
                out[(size_t)row * 128 + c] = val;
            }
        }
    }
}

// ---------------------------------------------------------------------------
// CSR construction: zero counters -> histogram -> scan -> scatter.
// ---------------------------------------------------------------------------
__global__ __launch_bounds__(256) void zero_counts(int* __restrict__ cu,
                                                   int* __restrict__ cv)
{
    int i = blockIdx.x * 256 + threadIdx.x;
    if (i < NNODE) { cu[i] = 0; cv[i] = 0; }
}

__global__ __launch_bounds__(256) void hist_kernel(
    const int* __restrict__ u_idx, const int* __restrict__ v_idx,
    int* __restrict__ cnt_u, int* __restrict__ cnt_v)
{
    int e = blockIdx.x * 256 + threadIdx.x;
    if (e < NEDGE) {
        atomicAdd(&cnt_u[u_idx[e]], 1);
        atomicAdd(&cnt_v[v_idx[e]], 1);
    }
}

// grid=2: block 0 scans u counts, block 1 scans v counts.
// Exclusive scan of 50000 counts with one 1024-thread block.
__global__ __launch_bounds__(1024) void scan_counts(
    const int* __restrict__ cu, int* __restrict__ su, int* __restrict__ curu,
    const int* __restrict__ cv, int* __restrict__ sv, int* __restrict__ curv)
{
    const int* cnt  = blockIdx.x ? cv   : cu;
    int* start      = blockIdx.x ? sv   : su;
    int* cursor     = blockIdx.x ? curv : curu;

    __shared__ int sums[1024];
    const int tid = threadIdx.x;
    const int C = (NNODE + 1023) / 1024; // 49
    int lo = tid * C;
    int hi = lo + C; if (hi > NNODE) hi = NNODE;
    int local = 0;
    for (int i = lo; i < hi; ++i) local += cnt[i];
    sums[tid] = local;
    __syncthreads();
    // Hillis-Steele inclusive scan over 1024 partials
    for (int ofs = 1; ofs < 1024; ofs <<= 1) {
        int v = (tid >= ofs) ? sums[tid - ofs] : 0;
        __syncthreads();
        sums[tid] += v;
        __syncthreads();
    }
    int run = (tid == 0) ? 0 : sums[tid - 1]; // exclusive prefix
    for (int i = lo; i < hi; ++i) {
        start[i] = run;
        cursor[i] = run;
        run += cnt[i];
    }
    if (tid == 1023) start[NNODE] = sums[1023]; // == NEDGE
}

__global__ __launch_bounds__(256) void scatter_kernel(
    const int* __restrict__ u_idx, const int* __restrict__ v_idx,
    int* __restrict__ cur_u, int* __restrict__ cur_v,
    int* __restrict__ el_u, int* __restrict__ el_v)
{
    int e = blockIdx.x * 256 + threadIdx.x;
    if (e < NEDGE) {
        int pu = atomicAdd(&cur_u[u_idx[e]], 1);
        el_u[pu] = e;
        int pv = atomicAdd(&cur_v[v_idx[e]], 1);
        el_v[pv] = e;
    }
}

// ---------------------------------------------------------------------------
// Per-destination-node attention aggregate, zero atomics.
// One wave per node (4 waves/block). Lane j covers features j, j+64, j+128:
//   h[f] = (f<128 ? he_src[src][f] : e_feat[e][f-128])
//   x[f] = h[f] * h_att[n][f]
//   agg[n][f] = sum_e(h*exp(x-m)) / sum_e(exp(x-m)),  m = per-feature seg max
// Two passes over the segment (max, then exp-sum); second pass re-reads
// lines that are L1/L2 hot. Segment edge/src ids are fetched once by lanes
// 0..deg-1 and broadcast via __shfl.
// ---------------------------------------------------------------------------
__global__ __launch_bounds__(256) void attn_node(
    const float* __restrict__ e_feat, const int* __restrict__ elist,
    const int* __restrict__ start, const int* __restrict__ other_idx,
    const bf16* __restrict__ he_src, const bf16* __restrict__ h_att,
    bf16* __restrict__ agg)
{
    const int wave = threadIdx.x >> 6, j = threadIdx.x & 63;
    const int n = blockIdx.x * 4 + wave;
    if (n >= NNODE) return;

    const bf16* ha = h_att + (size_t)n * 192;
    const float ha0 = b2f(ha[j]);
    const float ha1 = b2f(ha[j + 64]);
    const float ha2 = b2f(ha[j + 128]);

    const int s0 = start[n], s1 = start[n + 1];
    const int deg = s1 - s0;

    // lanes cooperatively fetch up to 64 (edge, src) pairs
    int e_l = 0, src_l = 0;
    if (j < deg) {
        e_l = elist[s0 + j];
        src_l = other_idx[e_l];
    }

    const float NEG_INF = __int_as_float(0xFF800000);
    float m0 = NEG_INF, m1 = NEG_INF, m2 = NEG_INF;
    for (int k = 0; k < deg; ++k) {
        int e, s;
        if (k < 64) { e = __shfl(e_l, k, 64); s = __shfl(src_l, k, 64); }
        else        { e = elist[s0 + k];      s = other_idx[e]; }
        const bf16* hs = he_src + (size_t)s * 128;
        float h0 = b2f(hs[j]);
        float h1 = b2f(hs[j + 64]);
        float h2 = e_feat[(size_t)e * 64 + j];
        m0 = fmaxf(m0, h0 * ha0);
        m1 = fmaxf(m1, h1 * ha1);
        m2 = fmaxf(m2, h2 * ha2);
    }

    float sum0 = 0.f, sum1 = 0.f, sum2 = 0.f;
    float t0 = 0.f, t1 = 0.f, t2 = 0.f;
    for (int k = 0; k < deg; ++k) {
        int e, s;
        if (k < 64) { e = __shfl(e_l, k, 64); s = __shfl(src_l, k, 64); }
        else        { e = elist[s0 + k];      s = other_idx[e]; }
        const bf16* hs = he_src + (size_t)s * 128;
        float h0 = b2f(hs[j]);
        float h1 = b2f(hs[j + 64]);
        float h2 = e_feat[(size_t)e * 64 + j];
        float e0 = __expf(h0 * ha0 - m0);
        float e1 = __expf(h1 * ha1 - m1);
        float e2 = __expf(h2 * ha2 - m2);
        sum0 += e0; t0 += h0 * e0;
        sum1 += e1; t1 += h1 * e1;
        sum2 += e2; t2 += h2 * e2;
    }

    bf16* ag = agg + (size_t)n * 192;
    ag[j]       = __float2bfloat16(sum0 > 0.f ? t0 / sum0 : 0.f);
    ag[j + 64]  = __float2bfloat16(sum1 > 0.f ? t1 / sum1 : 0.f);
    ag[j + 128] = __float2bfloat16(sum2 > 0.f ? t2 / sum2 : 0.f);
}

// ---------------------------------------------------------------------------

extern "C" void kernel_launch(void* const* d_in, const int* in_sizes, int n_in,
                              void* d_out, int out_size, void* d_ws, size_t ws_size,
                              hipStream_t stream)
{
    const float* e_feat   = (const float*)d_in[0];
    const float* u_feat   = (const float*)d_in[1];
    const float* v_feat   = (const float*)d_in[2];
    const int*   u_idx    = (const int*)d_in[3];
    const int*   v_idx    = (const int*)d_in[4];
    const float* e_lin_w  = (const float*)d_in[5];
    const float* e_lin_b  = (const float*)d_in[6];
    const float* u_lin_w  = (const float*)d_in[7];
    const float* u_lin_b  = (const float*)d_in[8];
    const float* v_lin_w  = (const float*)d_in[9];
    const float* v_lin_b  = (const float*)d_in[10];
    const float* attn_u_w = (const float*)d_in[11];
    const float* attn_u_b = (const float*)d_in[12];
    const float* attn_v_w = (const float*)d_in[13];
    const float* attn_v_b = (const float*)d_in[14];
    const float* W_u_w    = (const float*)d_in[15];
    const float* W_u_b    = (const float*)d_in[16];
    const float* W_v_w    = (const float*)d_in[17];
    const float* W_v_b    = (const float*)d_in[18];
    const float* Vu_w     = (const float*)d_in[19];
    const float* Vu_b     = (const float*)d_in[20];
    const float* Vv_w     = (const float*)d_in[21];
    const float* Vv_b     = (const float*)d_in[22];

    float* out = (float*)d_out;
    float* hu_out = out + (size_t)NEDGE * 128;
    float* hv_out = hu_out + (size_t)NUN * 128;

    // workspace carve-out (~110 MB)
    char* ws = (char*)d_ws;
    size_t off = 0;
    auto alloc = [&](size_t bytes) -> char* {
        char* p = ws + off;
        off += (bytes + 255) & ~(size_t)255;
        return p;
    };
    bf16* he_u_b = (bf16*)alloc((size_t)NUN * 128 * 2);
    bf16* he_v_b = (bf16*)alloc((size_t)NVN * 128 * 2);
    bf16* hau_b  = (bf16*)alloc((size_t)NUN * 192 * 2);
    bf16* hav_b  = (bf16*)alloc((size_t)NVN * 192 * 2);
    bf16* aggu_b = (bf16*)alloc((size_t)NUN * 192 * 2);
    bf16* aggv_b = (bf16*)alloc((size_t)NVN * 192 * 2);
    int* cnt_u   = (int*)alloc((size_t)NNODE * 4);
    int* cnt_v   = (int*)alloc((size_t)NNODE * 4);
    int* start_u = (int*)alloc((size_t)(NNODE + 1) * 4);
    int* start_v = (int*)alloc((size_t)(NNODE + 1) * 4);
    int* cur_u   = (int*)alloc((size_t)NNODE * 4);
    int* cur_v   = (int*)alloc((size_t)NNODE * 4);
    int* el_u    = (int*)alloc((size_t)NEDGE * 4);
    int* el_v    = (int*)alloc((size_t)NEDGE * 4);

    dim3 blk(256);
    const int gnode = (NUN + 63) / 64;          // 782
    const int gedge_gemm = (NEDGE + 63) / 64;   // 7813
    const int gzero = (NNODE + 255) / 256;      // 196
    const int gedge1 = (NEDGE + 255) / 256;     // 1954
    const int gattn = (NNODE + 3) / 4;          // 12500

    // CSR build (independent of GEMMs)
    zero_counts<<<gzero, blk, 0, stream>>>(cnt_u, cnt_v);
    hist_kernel<<<gedge1, blk, 0, stream>>>(u_idx, v_idx, cnt_u, cnt_v);
    scan_counts<<<2, dim3(1024), 0, stream>>>(cnt_u, start_u, cur_u,
                                              cnt_v, start_v, cur_v);
    scatter_kernel<<<gedge1, blk, 0, stream>>>(u_idx, v_idx, cur_u, cur_v, el_u, el_v);

    // node linears
    gemm_node<false, true><<<gnode, blk, 0, stream>>>(u_feat, u_lin_w, u_lin_b, NUN, 128, 128, he_u_b, 128, 0);
    gemm_node<false, true><<<gnode, blk, 0, stream>>>(v_feat, v_lin_w, v_lin_b, NVN, 128, 128, he_v_b, 128, 0);
    gemm_node<false, true><<<gnode, blk, 0, stream>>>(u_feat, attn_u_w, attn_u_b, NUN, 128, 192, hau_b, 192, 0);
    gemm_node<false, true><<<gnode, blk, 0, stream>>>(v_feat, attn_v_w, attn_v_b, NVN, 128, 192, hav_b, 192, 0);
    gemm_node<false, false><<<gnode, blk, 0, stream>>>(u_feat, Vu_w, Vu_b, NUN, 128, 64, hu_out, 128, 0);
    gemm_node<false, false><<<gnode, blk, 0, stream>>>(v_feat, Vv_w, Vv_b, NVN, 128, 64, hv_out, 128, 0);

    // he output (edge GEMM + endpoint gather-add)
    gemm_edge<<<gedge_gemm, blk, 0, stream>>>(e_feat, e_lin_w, e_lin_b, u_idx, v_idx,
                                              he_u_b, he_v_b, out);

    // u-side (backward: v -> u, dst = u_idx, src = v_idx)
    attn_node<<<gattn, blk, 0, stream>>>(e_feat, el_u, start_u, v_idx, he_v_b, hau_b, aggu_b);
    gemm_node<true, false><<<gnode, blk, 0, stream>>>(aggu_b, W_u_w, W_u_b, NUN, 192, 64, hu_out, 128, 64);

    // v-side (forward: u -> v, dst = v_idx, src = u_idx)
    attn_node<<<gattn, blk, 0, stream>>>(e_feat, el_v, start_v, u_idx, he_u_b, hav_b, aggv_b);
    gemm_node<true, false><<<gnode, blk, 0, stream>>>(aggv_b, W_v_w, W_v_b, NVN, 192, 64, hv_out, 128, 64);
}

// Round 3
// 967.088 us; speedup vs baseline: 1.4075x; 1.4075x over previous
//
#include <hip/hip_runtime.h>
#include <hip/hip_bf16.h>
#include <stdint.h>

typedef __hip_bfloat16 bf16;
typedef __bf16 bf16x8 __attribute__((ext_vector_type(8)));
typedef float f32x4 __attribute__((ext_vector_type(4)));

#define NEDGE 500000
#define NUN   50000
#define NVN   50000
#define NNODE 50000   // == NUN == NVN

__device__ __forceinline__ float b2f(bf16 v) { return __bfloat162float(v); }

// ---------------------------------------------------------------------------
// Weight prep: 9 matrices, f32 [din][dout] -> bf16 [dout][din] (transposed).
// Coalesced reads, scattered 2B writes (total only 131072 elements).
// ---------------------------------------------------------------------------
struct PrepArgs {
    const float* src[9];
    bf16*        dst[9];
    int din[9], dout[9];
};

__global__ __launch_bounds__(256) void prep_w(PrepArgs a)
{
    const int y = blockIdx.y;
    const float* src = a.src[y];
    bf16*        dst = a.dst[y];
    const int din = a.din[y], dout = a.dout[y];
    int idx = blockIdx.x * 256 + threadIdx.x;
    if (idx < din * dout) {
        int k = idx / dout, n = idx - k * dout;
        dst[n * din + k] = __float2bfloat16(src[idx]);
    }
}

// ---------------------------------------------------------------------------
// Fused 6-way node GEMM (din=128 for all): C[N,dout] = A[N,128] @ W + b.
// blockIdx.y selects the matrix. Weights pre-transposed bf16 [dout][128];
// staged into padded LDS (stride 136) with coalesced 16B copies.
// MFMA 16x16x32 bf16; A frag A[m=lane&15][k=quad*8+j]; C/D col=lane&15,
// row=quad*4+reg (m89-verified).
// ---------------------------------------------------------------------------
struct G6 {
    const float* A[6];
    const bf16*  Wt[6];
    const float* bias[6];
    void*        out[6];
    int dout[6], ostride[6], ocol[6], obf[6];
};

__global__ __launch_bounds__(256) void gemm_fused6(G6 g)
{
    __shared__ __align__(16) bf16 wt[192 * 136]; // 52224 B max
    const int y = blockIdx.y;
    const int tid = threadIdx.x;
    const bf16* Wt = g.Wt[y];
    const int dout = g.dout[y];

    for (int i = tid; i < dout * 16; i += 256) { // 16 chunks of 8 bf16 per row
        int n = i >> 4, kc = i & 15;
        *(bf16x8*)&wt[n * 136 + kc * 8] = *(const bf16x8*)&Wt[n * 128 + kc * 8];
    }

    const int wave = tid >> 6, lane = tid & 63;
    const int m16 = lane & 15, quad = lane >> 4;
    const int row0 = blockIdx.x * 64 + wave * 16;
    int arow = row0 + m16; if (arow >= NNODE) arow = NNODE - 1;
    const float* ap = g.A[y] + (size_t)arow * 128 + quad * 8;

    bf16x8 afr[4];
    #pragma unroll
    for (int ks = 0; ks < 4; ++ks) {
        float4 f0 = *(const float4*)(ap + ks * 32);
        float4 f1 = *(const float4*)(ap + ks * 32 + 4);
        afr[ks][0] = (__bf16)f0.x; afr[ks][1] = (__bf16)f0.y;
        afr[ks][2] = (__bf16)f0.z; afr[ks][3] = (__bf16)f0.w;
        afr[ks][4] = (__bf16)f1.x; afr[ks][5] = (__bf16)f1.y;
        afr[ks][6] = (__bf16)f1.z; afr[ks][7] = (__bf16)f1.w;
    }
    __syncthreads();

    const float* bias = g.bias[y];
    void* outp = g.out[y];
    const int ostr = g.ostride[y], ocol = g.ocol[y], obf = g.obf[y];
    const int nct = dout >> 4;
    for (int ct = 0; ct < nct; ++ct) {
        f32x4 acc = {0.f, 0.f, 0.f, 0.f};
        const bf16* bb = &wt[(ct * 16 + m16) * 136 + quad * 8];
        #pragma unroll
        for (int ks = 0; ks < 4; ++ks)
            acc = __builtin_amdgcn_mfma_f32_16x16x32_bf16(afr[ks], *(const bf16x8*)(bb + ks * 32), acc, 0, 0, 0);
        const int c = ct * 16 + m16;
        const float bv = bias[c];
        #pragma unroll
        for (int r = 0; r < 4; ++r) {
            int row = row0 + quad * 4 + r;
            if (row < NNODE) {
                size_t idx = (size_t)row * ostr + ocol + c;
                float val = acc[r] + bv;
                if (obf) ((bf16*)outp)[idx] = __float2bfloat16(val);
                else     ((float*)outp)[idx] = val;
            }
        }
    }
}

// ---------------------------------------------------------------------------
// Fused 2-way tail GEMM: A bf16 [N,192] (agg), Wt bf16 [64][192], out f32
// columns 64..127 of hu/hv. LDS stride 200 (16B-aligned rows).
// ---------------------------------------------------------------------------
struct G2 {
    const bf16*  A[2];
    const bf16*  Wt[2];
    const float* bias[2];
    float*       out[2];
};

__global__ __launch_bounds__(256) void gemm_fused2(G2 g)
{
    __shared__ __align__(16) bf16 wt[64 * 200]; // 25600 B
    const int y = blockIdx.y;
    const int tid = threadIdx.x;
    const bf16* Wt = g.Wt[y];

    for (int i = tid; i < 64 * 24; i += 256) { // 24 chunks of 8 bf16 per row
        int n = i / 24, kc = i - n * 24;
        *(bf16x8*)&wt[n * 200 + kc * 8] = *(const bf16x8*)&Wt[n * 192 + kc * 8];
    }

    const int wave = tid >> 6, lane = tid & 63;
    const int m16 = lane & 15, quad = lane >> 4;
    const int row0 = blockIdx.x * 64 + wave * 16;
    int arow = row0 + m16; if (arow >= NNODE) arow = NNODE - 1;
    const bf16* ap = g.A[y] + (size_t)arow * 192 + quad * 8;

    bf16x8 afr[6];
    #pragma unroll
    for (int ks = 0; ks < 6; ++ks) afr[ks] = *(const bf16x8*)(ap + ks * 32);
    __syncthreads();

    const float* bias = g.bias[y];
    float* outp = g.out[y];
    for (int ct = 0; ct < 4; ++ct) {
        f32x4 acc = {0.f, 0.f, 0.f, 0.f};
        const bf16* bb = &wt[(ct * 16 + m16) * 200 + quad * 8];
        #pragma unroll
        for (int ks = 0; ks < 6; ++ks)
            acc = __builtin_amdgcn_mfma_f32_16x16x32_bf16(afr[ks], *(const bf16x8*)(bb + ks * 32), acc, 0, 0, 0);
        const int c = ct * 16 + m16;
        const float bv = bias[c];
        #pragma unroll
        for (int r = 0; r < 4; ++r) {
            int row = row0 + quad * 4 + r;
            if (row < NNODE)
                outp[(size_t)row * 128 + 64 + c] = acc[r] + bv;
        }
    }
}

// ---------------------------------------------------------------------------
// Edge GEMM fused with gather-add epilogue. he endpoint rows are staged into
// LDS with 16B vector gathers (8 per thread) instead of 2M scattered 2B loads.
// ---------------------------------------------------------------------------
__global__ __launch_bounds__(256) void gemm_edge(
    const float* __restrict__ A, const bf16* __restrict__ Wt,
    const float* __restrict__ bias,
    const int* __restrict__ u_idx, const int* __restrict__ v_idx,
    const bf16* __restrict__ he_u, const bf16* __restrict__ he_v,
    float* __restrict__ out)
{
    __shared__ __align__(16) bf16 wt[128 * 72];    // 18432 B
    __shared__ __align__(16) bf16 ghe[2 * 64 * 136]; // 34816 B
    __shared__ int nid[128];                        // [0..63]=u, [64..127]=v
    const int tid = threadIdx.x;
    const int blk0 = blockIdx.x * 64;

    if (tid < 128) {
        int r = tid & 63;
        int row = blk0 + r; if (row >= NEDGE) row = NEDGE - 1;
        nid[tid] = (tid < 64) ? u_idx[row] : v_idx[row];
    }
    // weight staging (independent of nid)
    for (int i = tid; i < 128 * 8; i += 256) {
        int n = i >> 3, kc = i & 7;
        *(bf16x8*)&wt[n * 72 + kc * 8] = *(const bf16x8*)&Wt[n * 64 + kc * 8];
    }
    __syncthreads();

    // gather staging: 2048 chunks of 16B
    for (int i = tid; i < 2048; i += 256) {
        int side = i >> 10, rem = i & 1023, r = rem >> 4, c = rem & 15;
        int node = nid[side * 64 + r];
        const bf16* src = (side ? he_v : he_u) + (size_t)node * 128 + c * 8;
        *(bf16x8*)&ghe[(side * 64 + r) * 136 + c * 8] = *(const bf16x8*)src;
    }

    const int wave = tid >> 6, lane = tid & 63;
    const int m16 = lane & 15, quad = lane >> 4;
    const int row0 = blk0 + wave * 16;
    int arow = row0 + m16; if (arow >= NEDGE) arow = NEDGE - 1;
    const float* ap = A + (size_t)arow * 64 + quad * 8;

    bf16x8 af0, af1;
    {
        float4 f0 = *(const float4*)(ap);
        float4 f1 = *(const float4*)(ap + 4);
        af0[0] = (__bf16)f0.x; af0[1] = (__bf16)f0.y;
        af0[2] = (__bf16)f0.z; af0[3] = (__bf16)f0.w;
        af0[4] = (__bf16)f1.x; af0[5] = (__bf16)f1.y;
        af0[6] = (__bf16)f1.z; af0[7] = (__bf16)f1.w;
        float4 f2 = *(const float4*)(ap + 32);
        float4 f3 = *(const float4*)(ap + 36);
        af1[0] = (__bf16)f2.x; af1[1] = (__bf16)f2.y;
        af1[2] = (__bf16)f2.z; af1[3] = (__bf16)f2.w;
        af1[4] = (__bf16)f3.x; af1[5] = (__bf16)f3.y;
        af1[6] = (__bf16)f3.z; af1[7] = (__bf16)f3.w;
    }
    __syncthreads();

    for (int ct = 0; ct < 8; ++ct) {
        f32x4 acc = {0.f, 0.f, 0.f, 0.f};
        const bf16* bb = &wt[(ct * 16 + m16) * 72 + quad * 8];
        acc = __builtin_amdgcn_mfma_f32_16x16x32_bf16(af0, *(const bf16x8*)(bb), acc, 0, 0, 0);
        acc = __builtin_amdgcn_mfma_f32_16x16x32_bf16(af1, *(const bf16x8*)(bb + 32), acc, 0, 0, 0);
        const int c = ct * 16 + m16;
        const float bv = bias[c];
        #pragma unroll
        for (int r = 0; r < 4; ++r) {
            int row = row0 + quad * 4 + r;
            if (row < NEDGE) {
                int rl = wave * 16 + quad * 4 + r;
                float val = acc[r] + bv
                          + b2f(ghe[rl * 136 + c])
                          + b2f(ghe[(64 + rl) * 136 + c]);
                out[(size_t)row * 128 + c] = val;
            }
        }
    }
}

// ---------------------------------------------------------------------------
// CSR construction: zero counters -> histogram -> scan -> scatter.
// Scatter also emits CSR-ordered src lists (removes dependent gather later).
// ---------------------------------------------------------------------------
__global__ __launch_bounds__(256) void zero_counts(int* __restrict__ cu,
                                                   int* __restrict__ cv)
{
    int i = blockIdx.x * 256 + threadIdx.x;
    if (i < NNODE) { cu[i] = 0; cv[i] = 0; }
}

__global__ __launch_bounds__(256) void hist_kernel(
    const int* __restrict__ u_idx, const int* __restrict__ v_idx,
    int* __restrict__ cnt_u, int* __restrict__ cnt_v)
{
    int e = blockIdx.x * 256 + threadIdx.x;
    if (e < NEDGE) {
        atomicAdd(&cnt_u[u_idx[e]], 1);
        atomicAdd(&cnt_v[v_idx[e]], 1);
    }
}

__global__ __launch_bounds__(1024) void scan_counts(
    const int* __restrict__ cu, int* __restrict__ su, int* __restrict__ curu,
    const int* __restrict__ cv, int* __restrict__ sv, int* __restrict__ curv)
{
    const int* cnt  = blockIdx.x ? cv   : cu;
    int* start      = blockIdx.x ? sv   : su;
    int* cursor     = blockIdx.x ? curv : curu;

    __shared__ int sums[1024];
    const int tid = threadIdx.x;
    const int C = (NNODE + 1023) / 1024; // 49
    int lo = tid * C;
    int hi = lo + C; if (hi > NNODE) hi = NNODE;
    int local = 0;
    for (int i = lo; i < hi; ++i) local += cnt[i];
    sums[tid] = local;
    __syncthreads();
    for (int ofs = 1; ofs < 1024; ofs <<= 1) {
        int v = (tid >= ofs) ? sums[tid - ofs] : 0;
        __syncthreads();
        sums[tid] += v;
        __syncthreads();
    }
    int run = (tid == 0) ? 0 : sums[tid - 1];
    for (int i = lo; i < hi; ++i) {
        start[i] = run;
        cursor[i] = run;
        run += cnt[i];
    }
    if (tid == 1023) start[NNODE] = sums[1023];
}

__global__ __launch_bounds__(256) void scatter_kernel(
    const int* __restrict__ u_idx, const int* __restrict__ v_idx,
    int* __restrict__ cur_u, int* __restrict__ cur_v,
    int* __restrict__ el_u, int* __restrict__ el_v,
    int* __restrict__ src_u, int* __restrict__ src_v)
{
    int e = blockIdx.x * 256 + threadIdx.x;
    if (e < NEDGE) {
        int u = u_idx[e], v = v_idx[e];
        int pu = atomicAdd(&cur_u[u], 1);
        el_u[pu] = e; src_u[pu] = v;
        int pv = atomicAdd(&cur_v[v], 1);
        el_v[pv] = e; src_v[pv] = u;
    }
}

// ---------------------------------------------------------------------------
// Per-destination attention aggregate, single pass (online softmax), zero
// atomics. One wave per node; lane j covers features j, j+64, j+128.
// ---------------------------------------------------------------------------
__global__ __launch_bounds__(256) void attn_node(
    const float* __restrict__ e_feat, const int* __restrict__ elist,
    const int* __restrict__ slist, const int* __restrict__ start,
    const bf16* __restrict__ he_src, const bf16* __restrict__ h_att,
    bf16* __restrict__ agg)
{
    const int wave = threadIdx.x >> 6, j = threadIdx.x & 63;
    const int n = blockIdx.x * 4 + wave;
    if (n >= NNODE) return;

    const bf16* ha = h_att + (size_t)n * 192;
    const float ha0 = b2f(ha[j]);
    const float ha1 = b2f(ha[j + 64]);
    const float ha2 = b2f(ha[j + 128]);

    const int s0 = start[n], deg = start[n + 1] - s0;

    int e_l = 0, s_l = 0;
    if (j < deg) { e_l = elist[s0 + j]; s_l = slist[s0 + j]; }

    const float NI = __int_as_float(0xFF800000); // -inf
    float m0 = NI, m1 = NI, m2 = NI;
    float su0 = 0.f, su1 = 0.f, su2 = 0.f;
    float t0 = 0.f, t1 = 0.f, t2 = 0.f;

    for (int k = 0; k < deg; ++k) {
        int e, s;
        if (k < 64) { e = __shfl(e_l, k, 64); s = __shfl(s_l, k, 64); }
        else        { e = elist[s0 + k];      s = slist[s0 + k]; }
        const bf16* hs = he_src + (size_t)s * 128;
        float h0 = b2f(hs[j]);
        float h1 = b2f(hs[j + 64]);
        float h2 = e_feat[(size_t)e * 64 + j];
        float x0 = h0 * ha0, x1 = h1 * ha1, x2 = h2 * ha2;
        float n0 = fmaxf(m0, x0), n1 = fmaxf(m1, x1), n2 = fmaxf(m2, x2);
        float c0 = __expf(m0 - n0), c1 = __expf(m1 - n1), c2 = __expf(m2 - n2);
        float p0 = __expf(x0 - n0), p1 = __expf(x1 - n1), p2 = __expf(x2 - n2);
        su0 = su0 * c0 + p0;  t0 = t0 * c0 + h0 * p0;
        su1 = su1 * c1 + p1;  t1 = t1 * c1 + h1 * p1;
        su2 = su2 * c2 + p2;  t2 = t2 * c2 + h2 * p2;
        m0 = n0; m1 = n1; m2 = n2;
    }

    bf16* ag = agg + (size_t)n * 192;
    ag[j]       = __float2bfloat16(su0 > 0.f ? t0 / su0 : 0.f);
    ag[j + 64]  = __float2bfloat16(su1 > 0.f ? t1 / su1 : 0.f);
    ag[j + 128] = __float2bfloat16(su2 > 0.f ? t2 / su2 : 0.f);
}

// ---------------------------------------------------------------------------

extern "C" void kernel_launch(void* const* d_in, const int* in_sizes, int n_in,
                              void* d_out, int out_size, void* d_ws, size_t ws_size,
                              hipStream_t stream)
{
    const float* e_feat   = (const float*)d_in[0];
    const float* u_feat   = (const float*)d_in[1];
    const float* v_feat   = (const float*)d_in[2];
    const int*   u_idx    = (const int*)d_in[3];
    const int*   v_idx    = (const int*)d_in[4];
    const float* e_lin_w  = (const float*)d_in[5];
    const float* e_lin_b  = (const float*)d_in[6];
    const float* u_lin_w  = (const float*)d_in[7];
    const float* u_lin_b  = (const float*)d_in[8];
    const float* v_lin_w  = (const float*)d_in[9];
    const float* v_lin_b  = (const float*)d_in[10];
    const float* attn_u_w = (const float*)d_in[11];
    const float* attn_u_b = (const float*)d_in[12];
    const float* attn_v_w = (const float*)d_in[13];
    const float* attn_v_b = (const float*)d_in[14];
    const float* W_u_w    = (const float*)d_in[15];
    const float* W_u_b    = (const float*)d_in[16];
    const float* W_v_w    = (const float*)d_in[17];
    const float* W_v_b    = (const float*)d_in[18];
    const float* Vu_w     = (const float*)d_in[19];
    const float* Vu_b     = (const float*)d_in[20];
    const float* Vv_w     = (const float*)d_in[21];
    const float* Vv_b     = (const float*)d_in[22];

    float* out = (float*)d_out;
    float* hu_out = out + (size_t)NEDGE * 128;
    float* hv_out = hu_out + (size_t)NUN * 128;

    char* ws = (char*)d_ws;
    size_t off = 0;
    auto alloc = [&](size_t bytes) -> char* {
        char* p = ws + off;
        off += (bytes + 255) & ~(size_t)255;
        return p;
    };
    bf16* he_u_b = (bf16*)alloc((size_t)NUN * 128 * 2);
    bf16* he_v_b = (bf16*)alloc((size_t)NVN * 128 * 2);
    bf16* hau_b  = (bf16*)alloc((size_t)NUN * 192 * 2);
    bf16* hav_b  = (bf16*)alloc((size_t)NVN * 192 * 2);
    bf16* aggu_b = (bf16*)alloc((size_t)NUN * 192 * 2);
    bf16* aggv_b = (bf16*)alloc((size_t)NVN * 192 * 2);
    int* cnt_u   = (int*)alloc((size_t)NNODE * 4);
    int* cnt_v   = (int*)alloc((size_t)NNODE * 4);
    int* start_u = (int*)alloc((size_t)(NNODE + 1) * 4);
    int* start_v = (int*)alloc((size_t)(NNODE + 1) * 4);
    int* cur_u   = (int*)alloc((size_t)NNODE * 4);
    int* cur_v   = (int*)alloc((size_t)NNODE * 4);
    int* el_u    = (int*)alloc((size_t)NEDGE * 4);
    int* el_v    = (int*)alloc((size_t)NEDGE * 4);
    int* src_u   = (int*)alloc((size_t)NEDGE * 4);
    int* src_v   = (int*)alloc((size_t)NEDGE * 4);
    // pre-transposed bf16 weights [dout][din]
    bf16* Wt_e  = (bf16*)alloc((size_t)128 * 64 * 2);
    bf16* Wt_u  = (bf16*)alloc((size_t)128 * 128 * 2);
    bf16* Wt_v  = (bf16*)alloc((size_t)128 * 128 * 2);
    bf16* Wt_au = (bf16*)alloc((size_t)192 * 128 * 2);
    bf16* Wt_av = (bf16*)alloc((size_t)192 * 128 * 2);
    bf16* Wt_Wu = (bf16*)alloc((size_t)64 * 192 * 2);
    bf16* Wt_Wv = (bf16*)alloc((size_t)64 * 192 * 2);
    bf16* Wt_Vu = (bf16*)alloc((size_t)64 * 128 * 2);
    bf16* Wt_Vv = (bf16*)alloc((size_t)64 * 128 * 2);

    dim3 blk(256);
    const int gnode = (NUN + 63) / 64;          // 782
    const int gedge_gemm = (NEDGE + 63) / 64;   // 7813
    const int gzero = (NNODE + 255) / 256;      // 196
    const int gedge1 = (NEDGE + 255) / 256;     // 1954
    const int gattn = (NNODE + 3) / 4;          // 12500

    // weight prep (independent of everything else)
    PrepArgs pa;
    pa.src[0] = e_lin_w;  pa.dst[0] = Wt_e;  pa.din[0] = 64;  pa.dout[0] = 128;
    pa.src[1] = u_lin_w;  pa.dst[1] = Wt_u;  pa.din[1] = 128; pa.dout[1] = 128;
    pa.src[2] = v_lin_w;  pa.dst[2] = Wt_v;  pa.din[2] = 128; pa.dout[2] = 128;
    pa.src[3] = attn_u_w; pa.dst[3] = Wt_au; pa.din[3] = 128; pa.dout[3] = 192;
    pa.src[4] = attn_v_w; pa.dst[4] = Wt_av; pa.din[4] = 128; pa.dout[4] = 192;
    pa.src[5] = W_u_w;    pa.dst[5] = Wt_Wu; pa.din[5] = 192; pa.dout[5] = 64;
    pa.src[6] = W_v_w;    pa.dst[6] = Wt_Wv; pa.din[6] = 192; pa.dout[6] = 64;
    pa.src[7] = Vu_w;     pa.dst[7] = Wt_Vu; pa.din[7] = 128; pa.dout[7] = 64;
    pa.src[8] = Vv_w;     pa.dst[8] = Wt_Vv; pa.din[8] = 128; pa.dout[8] = 64;
    prep_w<<<dim3(96, 9), blk, 0, stream>>>(pa);

    // CSR build
    zero_counts<<<gzero, blk, 0, stream>>>(cnt_u, cnt_v);
    hist_kernel<<<gedge1, blk, 0, stream>>>(u_idx, v_idx, cnt_u, cnt_v);
    scan_counts<<<2, dim3(1024), 0, stream>>>(cnt_u, start_u, cur_u,
                                              cnt_v, start_v, cur_v);
    scatter_kernel<<<gedge1, blk, 0, stream>>>(u_idx, v_idx, cur_u, cur_v,
                                               el_u, el_v, src_u, src_v);

    // fused node linears (6 matrices, all din=128, N=50000)
    G6 g6;
    g6.A[0] = u_feat; g6.Wt[0] = Wt_u;  g6.bias[0] = u_lin_b;  g6.out[0] = he_u_b; g6.dout[0] = 128; g6.ostride[0] = 128; g6.ocol[0] = 0; g6.obf[0] = 1;
    g6.A[1] = v_feat; g6.Wt[1] = Wt_v;  g6.bias[1] = v_lin_b;  g6.out[1] = he_v_b; g6.dout[1] = 128; g6.ostride[1] = 128; g6.ocol[1] = 0; g6.obf[1] = 1;
    g6.A[2] = u_feat; g6.Wt[2] = Wt_au; g6.bias[2] = attn_u_b; g6.out[2] = hau_b;  g6.dout[2] = 192; g6.ostride[2] = 192; g6.ocol[2] = 0; g6.obf[2] = 1;
    g6.A[3] = v_feat; g6.Wt[3] = Wt_av; g6.bias[3] = attn_v_b; g6.out[3] = hav_b;  g6.dout[3] = 192; g6.ostride[3] = 192; g6.ocol[3] = 0; g6.obf[3] = 1;
    g6.A[4] = u_feat; g6.Wt[4] = Wt_Vu; g6.bias[4] = Vu_b;     g6.out[4] = hu_out; g6.dout[4] = 64;  g6.ostride[4] = 128; g6.ocol[4] = 0; g6.obf[4] = 0;
    g6.A[5] = v_feat; g6.Wt[5] = Wt_Vv; g6.bias[5] = Vv_b;     g6.out[5] = hv_out; g6.dout[5] = 64;  g6.ostride[5] = 128; g6.ocol[5] = 0; g6.obf[5] = 0;
    gemm_fused6<<<dim3(gnode, 6), blk, 0, stream>>>(g6);

    // he output (edge GEMM + endpoint gather-add via LDS staging)
    gemm_edge<<<gedge_gemm, blk, 0, stream>>>(e_feat, Wt_e, e_lin_b, u_idx, v_idx,
                                              he_u_b, he_v_b, out);

    // attention aggregates (single-pass online softmax)
    attn_node<<<gattn, blk, 0, stream>>>(e_feat, el_u, src_u, start_u, he_v_b, hau_b, aggu_b);
    attn_node<<<gattn, blk, 0, stream>>>(e_feat, el_v, src_v, start_v, he_u_b, hav_b, aggv_b);

    // fused tail GEMMs (agg @ W_*), write columns 64..127 of hu/hv
    G2 g2;
    g2.A[0] = aggu_b; g2.Wt[0] = Wt_Wu; g2.bias[0] = W_u_b; g2.out[0] = hu_out;
    g2.A[1] = aggv_b; g2.Wt[1] = Wt_Wv; g2.bias[1] = W_v_b; g2.out[1] = hv_out;
    gemm_fused2<<<dim3(gnode, 2), blk, 0, stream>>>(g2);
}